// Round 2
// baseline (177.849 us; speedup 1.0000x reference)
//
#include <hip/hip_runtime.h>

// CovarianceLayer: x [B=64, C=4, T=8192, M=16] fp32 -> cov [B, C, 16, 16] fp32
// cov = (P - S S^T / T) / (T-1),  P = X^T X via mfma_f32_16x16x32_bf16.
//
// R11 = R10 resubmitted verbatim (two GPU-acquisition timeouts in a row;
// no counter data yet for this variant -- not stacking further untested
// changes).
//
// R10 = R9 with fully-contiguous NT reads. R9's lane map (rg=lane&15,
// g=lane>>4) made each load instruction consume only the low/high 64B of
// every 128B line (f4 idx 8rg+g, then +4). With nontemporal loads (no L2
// allocation) that risks fetching every 128B line twice -> 2x read
// amplification on a pure-stream kernel.
//
// Key invariance: the MFMA uses A==B (same fragment), so P = sum_k x_k x_k^T
// is invariant under ANY permutation of k-rows. We therefore pair rows
// (r, r+16) instead of (2r, 2r+1) in the bf16 k-pack: lane l loads f4
// [base+l] and [base+l+64] -- two perfectly contiguous 1KB instructions per
// round, each 128B line consumed exactly once by one instruction. Only the
// lane->(rg,g) decode and the shuffle-reduce offsets change; LDS swizzle,
// MFMA read roles, and the conflict-free profile are identical to R9.
//
// Per 32-row round: 2 coalesced NT float4 loads/lane, fp32 column sums
// (exact mean term), bf16 pack, swizzled wave-private LDS transpose (writes
// 2 lanes/bank = free, reads conflict-free b128), 1 MFMA (A==B fragment).
// No barriers in the main loop; block combine + finalize as in R3-R5.

constexpr int T_DIM = 8192;
constexpr int M_DIM = 16;
constexpr int BLOCK = 1024;                 // 16 waves, 1 block per (b,c)
constexpr int NWAVE = BLOCK / 64;           // 16
constexpr int T_PER_WAVE = T_DIM / NWAVE;   // 512 rows
constexpr int ROUNDS = T_PER_WAVE / 32;     // 16 rounds of 32 rows
constexpr int PF = 4;                       // prefetch depth

using bf16x8 = __attribute__((ext_vector_type(8))) short;
using f32x4  = __attribute__((ext_vector_type(4))) float;   // native vector

static __device__ inline unsigned pack_bf2(float lo, float hi) {
    // RNE fp32->bf16 for both, packed lo | hi<<16 (finite normal inputs)
    union { float f; unsigned u; } a{lo}, b{hi};
    unsigned ra = a.u + 0x7fffu + ((a.u >> 16) & 1u);
    unsigned rb = b.u + 0x7fffu + ((b.u >> 16) & 1u);
    return (ra >> 16) | (rb & 0xffff0000u);
}

__global__ __launch_bounds__(BLOCK)
void cov_kernel(const float* __restrict__ x, float* __restrict__ out) {
    const int bc   = blockIdx.x;
    const int tid  = threadIdx.x;
    const int wave = tid >> 6;
    const int lane = tid & 63;

    // staging roles (R10): lane covers rows rg and rg+16 (round-local),
    // cols 4g..4g+3.  rg = lane bits 2..5, g = lane bits 0..1, so load
    // addresses are base + lane (and +64) -- fully contiguous per instr.
    const int rg = lane >> 2;
    const int g  = lane & 3;
    // MFMA roles: col = m, k-rows q*8..q*8+7 (layout verified R3-R7)
    const int q  = lane >> 4;
    const int m  = lane & 15;

    __shared__ __align__(16) unsigned stage[NWAVE][2][256]; // 2x 1KB per wave
    __shared__ float Pred[NWAVE][256];
    __shared__ float Sred[NWAVE][M_DIM];
    __shared__ float Stot[M_DIM];

    const f32x4* __restrict__ xin =
        (const f32x4*)(x + (size_t)bc * (T_DIM * M_DIM));

    // float4 index of load 1; round stride = 32 rows = 128 f4.
    const int idx0 = wave * (T_PER_WAVE * 4) + lane;

    // LDS write offsets: granule = qw*16 + (col ^ qw), dword-in-granule = dq
    const int qw = rg >> 2, dq = rg & 3;
    // LDS read pointer: granule = q*16 + (m ^ q), 16B each
    const int roff = (q * 16 + (m ^ q)) * 4;

    f32x4 acc = {0.f, 0.f, 0.f, 0.f};
    float s0 = 0.f, s1 = 0.f, s2 = 0.f, s3 = 0.f;

    // Rotating prefetch buffers: rounds r..r+PF-1 in flight at all times.
    f32x4 buf0[PF], buf1[PF];
#pragma unroll
    for (int r = 0; r < PF; ++r) {
        buf0[r] = __builtin_nontemporal_load(&xin[idx0 + r * 128]);
        buf1[r] = __builtin_nontemporal_load(&xin[idx0 + r * 128 + 64]);
    }

#pragma unroll
    for (int r = 0; r < ROUNDS; ++r) {
        const f32x4 a0 = buf0[r % PF];   // row rg      , cols 4g..4g+3
        const f32x4 a1 = buf1[r % PF];   // row rg + 16 , cols 4g..4g+3
        if (r + PF < ROUNDS) {
            buf0[r % PF] =
                __builtin_nontemporal_load(&xin[idx0 + (r + PF) * 128]);
            buf1[r % PF] =
                __builtin_nontemporal_load(&xin[idx0 + (r + PF) * 128 + 64]);
        }

        s0 += a0[0] + a1[0];  s1 += a0[1] + a1[1];
        s2 += a0[2] + a1[2];  s3 += a0[3] + a1[3];
        // k-pair kp = rg holds (row rg, row rg+16): a k-permutation, which
        // is harmless because both MFMA operands are the same fragment.
        unsigned* wb = &stage[wave][r & 1][0];
        wb[(qw * 16 + ((4 * g + 0) ^ qw)) * 4 + dq] = pack_bf2(a0[0], a1[0]);
        wb[(qw * 16 + ((4 * g + 1) ^ qw)) * 4 + dq] = pack_bf2(a0[1], a1[1]);
        wb[(qw * 16 + ((4 * g + 2) ^ qw)) * 4 + dq] = pack_bf2(a0[2], a1[2]);
        wb[(qw * 16 + ((4 * g + 3) ^ qw)) * 4 + dq] = pack_bf2(a0[3], a1[3]);
        bf16x8 frag = *(const bf16x8*)&stage[wave][r & 1][roff];
        acc = __builtin_amdgcn_mfma_f32_16x16x32_bf16(frag, frag, acc, 0, 0, 0);
    }

    // Wave column sums: reduce over rg (lane bits 2..5); lanes rg==0 (0..3)
    // hold cols 4g..4g+3.
#pragma unroll
    for (int off = 4; off <= 32; off <<= 1) {
        s0 += __shfl_xor(s0, off, 64);
        s1 += __shfl_xor(s1, off, 64);
        s2 += __shfl_xor(s2, off, 64);
        s3 += __shfl_xor(s3, off, 64);
    }
    if (rg == 0) {
        Sred[wave][4 * g + 0] = s0;
        Sred[wave][4 * g + 1] = s1;
        Sred[wave][4 * g + 2] = s2;
        Sred[wave][4 * g + 3] = s3;
    }

    // Per-wave partial P into LDS. C/D layout: col = m, row = q*4 + reg.
#pragma unroll
    for (int r = 0; r < 4; ++r)
        Pred[wave][(q * 4 + r) * M_DIM + m] = acc[r];
    __syncthreads();

    if (tid < M_DIM) {
        float s = 0.f;
#pragma unroll
        for (int w = 0; w < NWAVE; ++w) s += Sred[w][tid];
        Stot[tid] = s;
    }
    __syncthreads();

    if (tid < 256) {
        float P = 0.f;
#pragma unroll
        for (int w = 0; w < NWAVE; ++w) P += Pred[w][tid];
        const int mi = tid >> 4;
        const int ni = tid & 15;
        const float cov = (P - Stot[mi] * Stot[ni] * (1.0f / (float)T_DIM))
                        * (1.0f / (float)(T_DIM - 1));
        out[(size_t)bc * 256 + tid] = cov;
    }
}

extern "C" void kernel_launch(void* const* d_in, const int* in_sizes, int n_in,
                              void* d_out, int out_size, void* d_ws, size_t ws_size,
                              hipStream_t stream) {
    const float* x = (const float*)d_in[0];
    float* out = (float*)d_out;
    const int n_bc = in_sizes[0] / (T_DIM * M_DIM);   // B*C = 256
    cov_kernel<<<dim3(n_bc), dim3(BLOCK), 0, stream>>>(x, out);
}